// Round 2
// baseline (724.307 us; speedup 1.0000x reference)
//
#include <hip/hip_runtime.h>

typedef _Float16 f16;
typedef __attribute__((ext_vector_type(8))) _Float16 f16x8;
typedef __attribute__((ext_vector_type(4))) _Float16 f16x4;
typedef __attribute__((ext_vector_type(4))) float f32x4;

#define MFMA16(a, b, c) __builtin_amdgcn_mfma_f32_16x16x32_f16(a, b, c, 0, 0, 0)

#define SCALE_F 0.17677669529663687f
#define NHEAD 12
#define NTOK 49
#define NBW 2048

// ---------------------------------------------------------------------------
// cast f32 -> f16 (vectorized x4)
// ---------------------------------------------------------------------------
__global__ void cast_f32_to_f16(const float* __restrict__ in, f16* __restrict__ out, int n4) {
    int i0 = blockIdx.x * 256 + threadIdx.x;
    int stride = gridDim.x * 256;
    for (int i = i0; i < n4; i += stride) {
        f32x4 v = ((const f32x4*)in)[i];
        f16x4 o;
#pragma unroll
        for (int e = 0; e < 4; ++e) o[e] = (f16)v[e];
        ((f16x4*)out)[i] = o;
    }
}

// ---------------------------------------------------------------------------
// precompute BM[w4][h][64][64] = rpb-bias + mask, padded with -1e30
// ---------------------------------------------------------------------------
__global__ void prep_bm(const float* __restrict__ rpb, const int* __restrict__ rel_idx,
                        const float* __restrict__ mask, float* __restrict__ bm) {
    int blk = blockIdx.x;           // w4*12 + h
    int w4 = blk / NHEAD, h = blk - w4 * NHEAD;
    for (int idx = threadIdx.x; idx < 4096; idx += 64) {
        int r = idx >> 6, c = idx & 63;
        float v = -1e30f;
        if (r < NTOK && c < NTOK)
            v = rpb[rel_idx[r * NTOK + c] * NHEAD + h] + mask[(w4 * NTOK + r) * NTOK + c];
        bm[(size_t)blk * 4096 + idx] = v;
    }
}

// ---------------------------------------------------------------------------
// GEMM: C[M][N] = A[M][K] @ B[N][K]^T + bias[N]
// 128x128 tile, BK=64, 256 threads (4 waves, 2x2 wave grid, 4x4 MFMA frags each)
// global_load_lds staging with 3-bit chunk XOR swizzle (conflict-free ds_read_b128)
// ---------------------------------------------------------------------------
template <typename OUT_T>
__global__ __launch_bounds__(256) void gemm_bt(const f16* __restrict__ A, const f16* __restrict__ B,
                                               const float* __restrict__ bias, OUT_T* __restrict__ C,
                                               int M, int N, int K) {
    __shared__ __align__(16) f16 As[128 * 64];
    __shared__ __align__(16) f16 Bs[128 * 64];
    const int m0 = blockIdx.y * 128, n0 = blockIdx.x * 128;
    const int tid = threadIdx.x;
    const int w = tid >> 6, l = tid & 63;
    const int wm = w >> 1, wn = w & 1;
    const int lr = l & 15, lg = l >> 4;
    const int sp = l & 7;

    f32x4 acc[4][4] = {};

    for (int k0 = 0; k0 < K; k0 += 64) {
        __syncthreads();
#pragma unroll
        for (int it = 0; it < 4; ++it) {
            int row = w * 32 + it * 8 + (l >> 3);
            int gchunk = sp ^ (row & 7);
            const f16* gA = A + (size_t)(m0 + row) * K + k0 + gchunk * 8;
            const f16* gB = B + (size_t)(n0 + row) * K + k0 + gchunk * 8;
            f16* lA = As + (w * 32 + it * 8) * 64;  // wave-uniform; HW adds lane*16B
            f16* lB = Bs + (w * 32 + it * 8) * 64;
            __builtin_amdgcn_global_load_lds((const __attribute__((address_space(1))) void*)gA,
                                             (__attribute__((address_space(3))) void*)lA, 16, 0, 0);
            __builtin_amdgcn_global_load_lds((const __attribute__((address_space(1))) void*)gB,
                                             (__attribute__((address_space(3))) void*)lB, 16, 0, 0);
        }
        __syncthreads();
#pragma unroll
        for (int ks = 0; ks < 2; ++ks) {
            f16x8 af[4], bfr[4];
#pragma unroll
            for (int mi = 0; mi < 4; ++mi) {
                int r = 64 * wm + 16 * mi + lr;
                int chunk = (lg + 4 * ks) ^ (r & 7);
                af[mi] = *(const f16x8*)(As + r * 64 + chunk * 8);
            }
#pragma unroll
            for (int ni = 0; ni < 4; ++ni) {
                int r = 64 * wn + 16 * ni + lr;
                int chunk = (lg + 4 * ks) ^ (r & 7);
                bfr[ni] = *(const f16x8*)(Bs + r * 64 + chunk * 8);
            }
#pragma unroll
            for (int mi = 0; mi < 4; ++mi)
#pragma unroll
                for (int ni = 0; ni < 4; ++ni)
                    acc[mi][ni] = MFMA16(af[mi], bfr[ni], acc[mi][ni]);
        }
    }
    // epilogue: C/D layout col=lane&15, row=(lane>>4)*4+reg [m89]
#pragma unroll
    for (int mi = 0; mi < 4; ++mi) {
#pragma unroll
        for (int ni = 0; ni < 4; ++ni) {
            int col = n0 + 64 * wn + 16 * ni + lr;
            float bv = bias[col];
#pragma unroll
            for (int reg = 0; reg < 4; ++reg) {
                int row = m0 + 64 * wm + 16 * mi + 4 * lg + reg;
                C[(size_t)row * N + col] = (OUT_T)(acc[mi][ni][reg] + bv);
            }
        }
    }
}

// ---------------------------------------------------------------------------
// fused attention: one block (1 wave) per (window, head)
// QK^T via MFMA (frags straight from global, L2-hot), wave-parallel softmax,
// P and V^T staged in XOR-swizzled LDS, MFMA PV for both value streams.
// ---------------------------------------------------------------------------
__global__ __launch_bounds__(64) void attn_kernel(const f16* __restrict__ qkv,
                                                  const f16* __restrict__ vse,
                                                  const float* __restrict__ bm_all,
                                                  f16* __restrict__ att_se, f16* __restrict__ att_de) {
    __shared__ __align__(16) f16 Vts[2][32 * 64];  // [stream][d][j] transposed V, swizzled
    __shared__ __align__(16) f16 Ps[64 * 64];      // P, swizzled

    const int bh = blockIdx.x;
    const int b = bh / NHEAD, h = bh - b * NHEAD;
    const int l = threadIdx.x;
    const int lr = l & 15, lg = l >> 4;
    const size_t wbase = (size_t)b * NTOK;

    // stage V_se / V_de transposed into LDS (swizzled by row d)
    for (int idx = l; idx < 2 * NTOK * 4; idx += 64) {
        int s = idx >= NTOK * 4;
        int t = idx - s * NTOK * 4;
        int j = t >> 2, part = t & 3;
        const f16* src = s ? (qkv + (wbase + j) * 1152 + 768 + h * 32 + part * 8)
                           : (vse + (wbase + j) * 384 + h * 32 + part * 8);
        f16x8 v = *(const f16x8*)src;
#pragma unroll
        for (int e = 0; e < 8; ++e) {
            int d = part * 8 + e;
            Vts[s][(d << 6) + (j ^ ((d & 7) << 3))] = v[e];
        }
    }
    // zero pad j = 49..63
    for (int idx = l; idx < 2 * 32 * 15; idx += 64) {
        int s = idx / 480;
        int t = idx - s * 480;
        int d = t / 15, j = NTOK + (t - d * 15);
        Vts[s][(d << 6) + (j ^ ((d & 7) << 3))] = (f16)0.f;
    }

    // QK^T : fragments directly from global (rows shared by 12 head-blocks -> L2)
    const size_t MAXROW = (size_t)NBW * NTOK - 1;
    f16x8 qa[4], kb[4];
#pragma unroll
    for (int mi = 0; mi < 4; ++mi) {
        size_t gi = wbase + 16 * mi + lr;
        if (gi > MAXROW) gi = MAXROW;
        qa[mi] = *(const f16x8*)(qkv + gi * 1152 + h * 32 + lg * 8);
    }
#pragma unroll
    for (int ni = 0; ni < 4; ++ni) {
        size_t gj = wbase + 16 * ni + lr;
        if (gj > MAXROW) gj = MAXROW;
        kb[ni] = *(const f16x8*)(qkv + gj * 1152 + 384 + h * 32 + lg * 8);
    }
    const f32x4 zero4 = {0.f, 0.f, 0.f, 0.f};
    f32x4 S[4][4];
#pragma unroll
    for (int mi = 0; mi < 4; ++mi)
#pragma unroll
        for (int ni = 0; ni < 4; ++ni)
            S[mi][ni] = MFMA16(qa[mi], kb[ni], zero4);

    // softmax (bias+mask from precomputed table; rows spread over 16-lane groups)
    const float* bmp = bm_all + (size_t)((b & 3) * NHEAD + h) * 4096;
#pragma unroll
    for (int mi = 0; mi < 4; ++mi) {
#pragma unroll
        for (int reg = 0; reg < 4; ++reg) {
            int r = 16 * mi + 4 * lg + reg;
            float v[4];
#pragma unroll
            for (int ni = 0; ni < 4; ++ni)
                v[ni] = S[mi][ni][reg] * SCALE_F + bmp[(r << 6) + 16 * ni + lr];
            float mx = fmaxf(fmaxf(v[0], v[1]), fmaxf(v[2], v[3]));
#pragma unroll
            for (int off = 1; off < 16; off <<= 1) mx = fmaxf(mx, __shfl_xor(mx, off));
            float e[4];
            float sm = 0.f;
#pragma unroll
            for (int ni = 0; ni < 4; ++ni) {
                e[ni] = __expf(v[ni] - mx);
                sm += e[ni];
            }
#pragma unroll
            for (int off = 1; off < 16; off <<= 1) sm += __shfl_xor(sm, off);
            float inv = 1.f / sm;
#pragma unroll
            for (int ni = 0; ni < 4; ++ni)
                Ps[(r << 6) + ((16 * ni + lr) ^ ((r & 7) << 3))] = (f16)(e[ni] * inv);
        }
    }
    __syncthreads();

    // PV for both streams
    f32x4 o[2][4][2] = {};
#pragma unroll
    for (int ks = 0; ks < 2; ++ks) {
        f16x8 pa[4];
#pragma unroll
        for (int mi = 0; mi < 4; ++mi) {
            int r = 16 * mi + lr;
            pa[mi] = *(const f16x8*)(Ps + (r << 6) + ((8 * lg + 32 * ks) ^ ((r & 7) << 3)));
        }
#pragma unroll
        for (int s = 0; s < 2; ++s) {
#pragma unroll
            for (int ni = 0; ni < 2; ++ni) {
                int d = 16 * ni + lr;
                f16x8 vb = *(const f16x8*)(Vts[s] + (d << 6) + ((8 * lg + 32 * ks) ^ ((d & 7) << 3)));
#pragma unroll
                for (int mi = 0; mi < 4; ++mi) o[s][mi][ni] = MFMA16(pa[mi], vb, o[s][mi][ni]);
            }
        }
    }
    // write att outputs (layout (b, n, h, d) = rows of the proj GEMM)
#pragma unroll
    for (int s = 0; s < 2; ++s) {
        f16* dst = s ? att_de : att_se;
#pragma unroll
        for (int mi = 0; mi < 4; ++mi) {
#pragma unroll
            for (int reg = 0; reg < 4; ++reg) {
                int r = 16 * mi + 4 * lg + reg;
                if (r < NTOK) {
#pragma unroll
                    for (int ni = 0; ni < 2; ++ni)
                        dst[(wbase + r) * 384 + h * 32 + 16 * ni + lr] = (f16)o[s][mi][ni][reg];
                }
            }
        }
    }
}

// ---------------------------------------------------------------------------
extern "C" void kernel_launch(void* const* d_in, const int* in_sizes, int n_in,
                              void* d_out, int out_size, void* d_ws, size_t ws_size,
                              hipStream_t stream) {
    const float* se = (const float*)d_in[0];
    const float* de = (const float*)d_in[1];
    const float* mask = (const float*)d_in[2];
    const float* w_v_se = (const float*)d_in[3];
    const float* b_v_se = (const float*)d_in[4];
    const float* w_qkv = (const float*)d_in[5];
    const float* b_qkv = (const float*)d_in[6];
    const float* w_proj_se = (const float*)d_in[7];
    const float* b_proj_se = (const float*)d_in[8];
    const float* w_proj_de = (const float*)d_in[9];
    const float* b_proj_de = (const float*)d_in[10];
    const float* rpb = (const float*)d_in[11];
    const int* rel_idx = (const int*)d_in[12];

    const size_t SE_ELEMS = (size_t)NBW * NTOK * 384;  // 38,535,168

    char* ws = (char*)d_ws;
    f16* de_h = (f16*)(ws);                   // later reused as att_se
    f16* se_h = (f16*)(ws + 77070336);        // later reused as att_de
    f16* qkv_h = (f16*)(ws + 154140672);      // (100352, 1152)
    f16* vse_h = (f16*)(ws + 385351680);      // (100352, 384)
    f16* wqkv_h = (f16*)(ws + 462422016);
    f16* wvse_h = (f16*)(ws + 463306752);
    f16* wpse_h = (f16*)(ws + 463601664);
    f16* wpde_h = (f16*)(ws + 463896576);
    float* bm = (float*)(ws + 464191488);

    auto cast = [&](const float* in, f16* out, size_t n) {
        int n4 = (int)(n / 4);
        int blocks = (n4 + 255) / 256;
        if (blocks > 2048) blocks = 2048;
        cast_f32_to_f16<<<blocks, 256, 0, stream>>>(in, out, n4);
    };
    cast(de, de_h, SE_ELEMS);
    cast(se, se_h, SE_ELEMS);
    cast(w_qkv, wqkv_h, (size_t)1152 * 384);
    cast(w_v_se, wvse_h, (size_t)384 * 384);
    cast(w_proj_se, wpse_h, (size_t)384 * 384);
    cast(w_proj_de, wpde_h, (size_t)384 * 384);

    prep_bm<<<48, 64, 0, stream>>>(rpb, rel_idx, mask, bm);

    // qkv = de @ w_qkv^T + b   (M=100352, N=1152, K=384)
    gemm_bt<f16><<<dim3(9, 784), 256, 0, stream>>>(de_h, wqkv_h, b_qkv, qkv_h, 100352, 1152, 384);
    // v_se = se @ w_v_se^T + b (M=100352, N=384, K=384)
    gemm_bt<f16><<<dim3(3, 784), 256, 0, stream>>>(se_h, wvse_h, b_v_se, vse_h, 100352, 384, 384);

    // attention: att_se -> de_h region, att_de -> se_h region
    attn_kernel<<<NBW * NHEAD, 64, 0, stream>>>(qkv_h, vse_h, bm, de_h, se_h);

    // projections straight into d_out (f32)
    gemm_bt<float><<<dim3(3, 784), 256, 0, stream>>>(de_h, wpse_h, b_proj_se, (float*)d_out, 100352, 384, 384);
    gemm_bt<float><<<dim3(3, 784), 256, 0, stream>>>(se_h, wpde_h, b_proj_de, (float*)d_out + SE_ELEMS, 100352,
                                                     384, 384);
}

// Round 3
// 681.839 us; speedup vs baseline: 1.0623x; 1.0623x over previous
//
#include <hip/hip_runtime.h>

typedef _Float16 f16;
typedef __attribute__((ext_vector_type(8))) _Float16 f16x8;
typedef __attribute__((ext_vector_type(4))) _Float16 f16x4;
typedef __attribute__((ext_vector_type(4))) float f32x4;

#define MFMA16(a, b, c) __builtin_amdgcn_mfma_f32_16x16x32_f16(a, b, c, 0, 0, 0)

#define SCALE_F 0.17677669529663687f
#define NHEAD 12
#define NTOK 49
#define NBW 2048

// ---------------------------------------------------------------------------
// cast f32 -> f16 (vectorized x4)
// ---------------------------------------------------------------------------
__global__ void cast_f32_to_f16(const float* __restrict__ in, f16* __restrict__ out, int n4) {
    int i0 = blockIdx.x * 256 + threadIdx.x;
    int stride = gridDim.x * 256;
    for (int i = i0; i < n4; i += stride) {
        f32x4 v = ((const f32x4*)in)[i];
        f16x4 o;
#pragma unroll
        for (int e = 0; e < 4; ++e) o[e] = (f16)v[e];
        ((f16x4*)out)[i] = o;
    }
}

// ---------------------------------------------------------------------------
// precompute BM[w4][h][64][64] = rpb-bias + mask, padded with -1e30
// ---------------------------------------------------------------------------
__global__ void prep_bm(const float* __restrict__ rpb, const int* __restrict__ rel_idx,
                        const float* __restrict__ mask, float* __restrict__ bm) {
    int blk = blockIdx.x;           // w4*12 + h
    int w4 = blk / NHEAD, h = blk - w4 * NHEAD;
    for (int idx = threadIdx.x; idx < 4096; idx += 64) {
        int r = idx >> 6, c = idx & 63;
        float v = -1e30f;
        if (r < NTOK && c < NTOK)
            v = rpb[rel_idx[r * NTOK + c] * NHEAD + h] + mask[(w4 * NTOK + r) * NTOK + c];
        bm[(size_t)blk * 4096 + idx] = v;
    }
}

// ---------------------------------------------------------------------------
// GEMM: C[M][N] = A[M][K] @ B[N][K]^T + bias[N]
// 128x128 tile, BK=64, 256 threads. XCD-aware bijective block swizzle (T1):
// consecutive same-A-panel tiles land on one XCD -> A panel is L2-local.
// nwg must be divisible by 8 (all our grids are).
// ---------------------------------------------------------------------------
template <typename OUT_T>
__global__ __launch_bounds__(256) void gemm_bt(const f16* __restrict__ A, const f16* __restrict__ B,
                                               const float* __restrict__ bias, OUT_T* __restrict__ C,
                                               int M, int N, int K) {
    __shared__ __align__(16) f16 As[128 * 64];
    __shared__ __align__(16) f16 Bs[128 * 64];
    const int nwg = gridDim.x * gridDim.y;
    int wg = blockIdx.y * gridDim.x + blockIdx.x;
    wg = (wg & 7) * (nwg >> 3) + (wg >> 3);
    const int m0 = (wg / gridDim.x) * 128, n0 = (wg % gridDim.x) * 128;
    const int tid = threadIdx.x;
    const int w = tid >> 6, l = tid & 63;
    const int wm = w >> 1, wn = w & 1;
    const int lr = l & 15, lg = l >> 4;
    const int sp = l & 7;

    f32x4 acc[4][4] = {};

    for (int k0 = 0; k0 < K; k0 += 64) {
        __syncthreads();
#pragma unroll
        for (int it = 0; it < 4; ++it) {
            int row = w * 32 + it * 8 + (l >> 3);
            int gchunk = sp ^ (row & 7);
            const f16* gA = A + (size_t)(m0 + row) * K + k0 + gchunk * 8;
            const f16* gB = B + (size_t)(n0 + row) * K + k0 + gchunk * 8;
            f16* lA = As + (w * 32 + it * 8) * 64;  // wave-uniform; HW adds lane*16B
            f16* lB = Bs + (w * 32 + it * 8) * 64;
            __builtin_amdgcn_global_load_lds((const __attribute__((address_space(1))) void*)gA,
                                             (__attribute__((address_space(3))) void*)lA, 16, 0, 0);
            __builtin_amdgcn_global_load_lds((const __attribute__((address_space(1))) void*)gB,
                                             (__attribute__((address_space(3))) void*)lB, 16, 0, 0);
        }
        __syncthreads();
#pragma unroll
        for (int ks = 0; ks < 2; ++ks) {
            f16x8 af[4], bfr[4];
#pragma unroll
            for (int mi = 0; mi < 4; ++mi) {
                int r = 64 * wm + 16 * mi + lr;
                int chunk = (lg + 4 * ks) ^ (r & 7);
                af[mi] = *(const f16x8*)(As + r * 64 + chunk * 8);
            }
#pragma unroll
            for (int ni = 0; ni < 4; ++ni) {
                int r = 64 * wn + 16 * ni + lr;
                int chunk = (lg + 4 * ks) ^ (r & 7);
                bfr[ni] = *(const f16x8*)(Bs + r * 64 + chunk * 8);
            }
#pragma unroll
            for (int mi = 0; mi < 4; ++mi)
#pragma unroll
                for (int ni = 0; ni < 4; ++ni)
                    acc[mi][ni] = MFMA16(af[mi], bfr[ni], acc[mi][ni]);
        }
    }
    // epilogue: C/D layout col=lane&15, row=(lane>>4)*4+reg [m89]
#pragma unroll
    for (int mi = 0; mi < 4; ++mi) {
#pragma unroll
        for (int ni = 0; ni < 4; ++ni) {
            int col = n0 + 64 * wn + 16 * ni + lr;
            float bv = bias[col];
#pragma unroll
            for (int reg = 0; reg < 4; ++reg) {
                int row = m0 + 64 * wm + 16 * mi + 4 * lg + reg;
                C[(size_t)row * N + col] = (OUT_T)(acc[mi][ni][reg] + bv);
            }
        }
    }
}

// ---------------------------------------------------------------------------
// fused attention: one block (1 wave) per (window, head)
// QK^T via MFMA (frags straight from global), wave-parallel softmax,
// P in XOR-swizzled LDS (8KB only), V fragments gathered directly from
// global (B-frag = 8 elems along j at fixed d; strided 2B loads, L2/HBM).
// Cross-window over-reads (j>=49) are multiplied by P=0 -> harmless; ws
// buffer ordering keeps them in-bounds.
// ---------------------------------------------------------------------------
__global__ __launch_bounds__(64) void attn_kernel(const f16* __restrict__ qkv,
                                                  const f16* __restrict__ vse,
                                                  const float* __restrict__ bm_all,
                                                  f16* __restrict__ att_se, f16* __restrict__ att_de) {
    __shared__ __align__(16) f16 Ps[64 * 64];      // P, swizzled

    const int bh = blockIdx.x;
    const int b = bh / NHEAD, h = bh - b * NHEAD;
    const int l = threadIdx.x;
    const int lr = l & 15, lg = l >> 4;
    const size_t wbase = (size_t)b * NTOK;

    // QK^T : fragments directly from global (no clamps; over-reads in-bounds of ws)
    f16x8 qa[4], kb[4];
#pragma unroll
    for (int mi = 0; mi < 4; ++mi)
        qa[mi] = *(const f16x8*)(qkv + (wbase + 16 * mi + lr) * 1152 + h * 32 + lg * 8);
#pragma unroll
    for (int ni = 0; ni < 4; ++ni)
        kb[ni] = *(const f16x8*)(qkv + (wbase + 16 * ni + lr) * 1152 + 384 + h * 32 + lg * 8);

    const f32x4 zero4 = {0.f, 0.f, 0.f, 0.f};
    f32x4 S[4][4];
    __builtin_amdgcn_s_setprio(1);
#pragma unroll
    for (int mi = 0; mi < 4; ++mi)
#pragma unroll
        for (int ni = 0; ni < 4; ++ni)
            S[mi][ni] = MFMA16(qa[mi], kb[ni], zero4);
    __builtin_amdgcn_s_setprio(0);

    // softmax (bias+mask from precomputed table; rows spread over 16-lane groups)
    const float* bmp = bm_all + (size_t)((b & 3) * NHEAD + h) * 4096;
#pragma unroll
    for (int mi = 0; mi < 4; ++mi) {
#pragma unroll
        for (int reg = 0; reg < 4; ++reg) {
            int r = 16 * mi + 4 * lg + reg;
            float v[4];
#pragma unroll
            for (int ni = 0; ni < 4; ++ni)
                v[ni] = S[mi][ni][reg] * SCALE_F + bmp[(r << 6) + 16 * ni + lr];
            float mx = fmaxf(fmaxf(v[0], v[1]), fmaxf(v[2], v[3]));
#pragma unroll
            for (int off = 1; off < 16; off <<= 1) mx = fmaxf(mx, __shfl_xor(mx, off));
            float e[4];
            float sm = 0.f;
#pragma unroll
            for (int ni = 0; ni < 4; ++ni) {
                e[ni] = __expf(v[ni] - mx);
                sm += e[ni];
            }
#pragma unroll
            for (int off = 1; off < 16; off <<= 1) sm += __shfl_xor(sm, off);
            float inv = 1.f / sm;
#pragma unroll
            for (int ni = 0; ni < 4; ++ni)
                Ps[(r << 6) + ((16 * ni + lr) ^ ((r & 7) << 3))] = (f16)(e[ni] * inv);
        }
    }
    __syncthreads();

    // PV, one value-stream at a time (halves accumulator liveness)
#pragma unroll
    for (int s = 0; s < 2; ++s) {
        const f16* vbase = s ? (qkv + wbase * 1152 + 768 + h * 32) : (vse + wbase * 384 + h * 32);
        const int RS = s ? 1152 : 384;
        f32x4 o[4][2] = {};
#pragma unroll
        for (int ks = 0; ks < 2; ++ks) {
            f16x8 pa[4];
#pragma unroll
            for (int mi = 0; mi < 4; ++mi) {
                int r = 16 * mi + lr;
                pa[mi] = *(const f16x8*)(Ps + (r << 6) + ((8 * lg + 32 * ks) ^ ((r & 7) << 3)));
            }
#pragma unroll
            for (int ni = 0; ni < 2; ++ni) {
                const f16* p = vbase + (size_t)(8 * lg + 32 * ks) * RS + 16 * ni + lr;
                f16x8 vb;
#pragma unroll
                for (int e = 0; e < 8; ++e) vb[e] = p[(size_t)e * RS];
                __builtin_amdgcn_s_setprio(1);
#pragma unroll
                for (int mi = 0; mi < 4; ++mi) o[mi][ni] = MFMA16(pa[mi], vb, o[mi][ni]);
                __builtin_amdgcn_s_setprio(0);
            }
        }
        f16* dst = s ? att_de : att_se;
#pragma unroll
        for (int mi = 0; mi < 4; ++mi) {
#pragma unroll
            for (int reg = 0; reg < 4; ++reg) {
                int r = 16 * mi + 4 * lg + reg;
                if (r < NTOK) {
#pragma unroll
                    for (int ni = 0; ni < 2; ++ni)
                        dst[(wbase + r) * 384 + h * 32 + 16 * ni + lr] = (f16)o[mi][ni][reg];
                }
            }
        }
    }
}

// ---------------------------------------------------------------------------
extern "C" void kernel_launch(void* const* d_in, const int* in_sizes, int n_in,
                              void* d_out, int out_size, void* d_ws, size_t ws_size,
                              hipStream_t stream) {
    const float* se = (const float*)d_in[0];
    const float* de = (const float*)d_in[1];
    const float* mask = (const float*)d_in[2];
    const float* w_v_se = (const float*)d_in[3];
    const float* b_v_se = (const float*)d_in[4];
    const float* w_qkv = (const float*)d_in[5];
    const float* b_qkv = (const float*)d_in[6];
    const float* w_proj_se = (const float*)d_in[7];
    const float* b_proj_se = (const float*)d_in[8];
    const float* w_proj_de = (const float*)d_in[9];
    const float* b_proj_de = (const float*)d_in[10];
    const float* rpb = (const float*)d_in[11];
    const int* rel_idx = (const int*)d_in[12];

    const size_t SE_ELEMS = (size_t)NBW * NTOK * 384;  // 38,535,168

    char* ws = (char*)d_ws;
    f16* de_h = (f16*)(ws);                   // later reused as att_se
    f16* se_h = (f16*)(ws + 77070336);        // later reused as att_de
    f16* qkv_h = (f16*)(ws + 154140672);      // (100352, 1152)
    f16* vse_h = (f16*)(ws + 385351680);      // (100352, 384)
    f16* wqkv_h = (f16*)(ws + 462422016);
    f16* wvse_h = (f16*)(ws + 463306752);
    f16* wpse_h = (f16*)(ws + 463601664);
    f16* wpde_h = (f16*)(ws + 463896576);
    float* bm = (float*)(ws + 464191488);

    auto cast = [&](const float* in, f16* out, size_t n) {
        int n4 = (int)(n / 4);
        int blocks = (n4 + 255) / 256;
        if (blocks > 2048) blocks = 2048;
        cast_f32_to_f16<<<blocks, 256, 0, stream>>>(in, out, n4);
    };
    cast(de, de_h, SE_ELEMS);
    cast(se, se_h, SE_ELEMS);
    cast(w_qkv, wqkv_h, (size_t)1152 * 384);
    cast(w_v_se, wvse_h, (size_t)384 * 384);
    cast(w_proj_se, wpse_h, (size_t)384 * 384);
    cast(w_proj_de, wpde_h, (size_t)384 * 384);

    prep_bm<<<48, 64, 0, stream>>>(rpb, rel_idx, mask, bm);

    // qkv = de @ w_qkv^T + b   (M=100352, N=1152, K=384)
    gemm_bt<f16><<<dim3(9, 784), 256, 0, stream>>>(de_h, wqkv_h, b_qkv, qkv_h, 100352, 1152, 384);
    // v_se = se @ w_v_se^T + b (M=100352, N=384, K=384)
    gemm_bt<f16><<<dim3(3, 784), 256, 0, stream>>>(se_h, wvse_h, b_v_se, vse_h, 100352, 384, 384);

    // attention: att_se -> de_h region, att_de -> se_h region
    attn_kernel<<<NBW * NHEAD, 64, 0, stream>>>(qkv_h, vse_h, bm, de_h, se_h);

    // projections straight into d_out (f32)
    gemm_bt<float><<<dim3(3, 784), 256, 0, stream>>>(de_h, wpse_h, b_proj_se, (float*)d_out, 100352, 384, 384);
    gemm_bt<float><<<dim3(3, 784), 256, 0, stream>>>(se_h, wpde_h, b_proj_de, (float*)d_out + SE_ELEMS, 100352,
                                                     384, 384);
}

// Round 4
// 613.766 us; speedup vs baseline: 1.1801x; 1.1109x over previous
//
#include <hip/hip_runtime.h>

typedef _Float16 f16;
typedef __attribute__((ext_vector_type(8))) _Float16 f16x8;
typedef __attribute__((ext_vector_type(4))) _Float16 f16x4;
typedef __attribute__((ext_vector_type(4))) float f32x4;

#define MFMA16(a, b, c) __builtin_amdgcn_mfma_f32_16x16x32_f16(a, b, c, 0, 0, 0)

#define SCALE_F 0.17677669529663687f
#define NHEAD 12
#define NTOK 49
#define NBW 2048

// ---------------------------------------------------------------------------
// cast f32 -> f16 (vectorized x4) — only used for the small weight matrices now
// ---------------------------------------------------------------------------
__global__ void cast_f32_to_f16(const float* __restrict__ in, f16* __restrict__ out, int n4) {
    int i0 = blockIdx.x * 256 + threadIdx.x;
    int stride = gridDim.x * 256;
    for (int i = i0; i < n4; i += stride) {
        f32x4 v = ((const f32x4*)in)[i];
        f16x4 o;
#pragma unroll
        for (int e = 0; e < 4; ++e) o[e] = (f16)v[e];
        ((f16x4*)out)[i] = o;
    }
}

// ---------------------------------------------------------------------------
// precompute BM[w4][h][64][64] = rpb-bias + mask, padded with -1e30
// ---------------------------------------------------------------------------
__global__ void prep_bm(const float* __restrict__ rpb, const int* __restrict__ rel_idx,
                        const float* __restrict__ mask, float* __restrict__ bm) {
    int blk = blockIdx.x;           // w4*12 + h
    int w4 = blk / NHEAD, h = blk - w4 * NHEAD;
    for (int idx = threadIdx.x; idx < 4096; idx += 64) {
        int r = idx >> 6, c = idx & 63;
        float v = -1e30f;
        if (r < NTOK && c < NTOK)
            v = rpb[rel_idx[r * NTOK + c] * NHEAD + h] + mask[(w4 * NTOK + r) * NTOK + c];
        bm[(size_t)blk * 4096 + idx] = v;
    }
}

// ---------------------------------------------------------------------------
// GEMM: C[M][N] = A[M][K] @ B[N][K]^T + bias[N]
// 128x128 tile, BK=64, 256 threads, XCD-aware bijective block swizzle (T1).
// A_F32: A is read as f32 and cast to f16 during reg-staging (fused cast);
// otherwise A is f16 via global_load_lds with pre-swizzled source.
// ---------------------------------------------------------------------------
template <typename OUT_T, bool A_F32>
__global__ __launch_bounds__(256) void gemm_bt(const void* __restrict__ Av, const f16* __restrict__ B,
                                               const float* __restrict__ bias, OUT_T* __restrict__ C,
                                               int M, int N, int K) {
    __shared__ __align__(16) f16 As[128 * 64];
    __shared__ __align__(16) f16 Bs[128 * 64];
    const int nwg = gridDim.x * gridDim.y;
    int wg = blockIdx.y * gridDim.x + blockIdx.x;
    wg = (wg & 7) * (nwg >> 3) + (wg >> 3);
    const int m0 = (wg / gridDim.x) * 128, n0 = (wg % gridDim.x) * 128;
    const int tid = threadIdx.x;
    const int w = tid >> 6, l = tid & 63;
    const int wm = w >> 1, wn = w & 1;
    const int lr = l & 15, lg = l >> 4;
    const int sp = l & 7;

    f32x4 acc[4][4] = {};

    for (int k0 = 0; k0 < K; k0 += 64) {
        __syncthreads();
        if constexpr (A_F32) {
            const float* A32 = (const float*)Av;
            f32x4 t0[4], t1[4];
#pragma unroll
            for (int it = 0; it < 4; ++it) {
                int row = w * 32 + it * 8 + (l >> 3);
                const float* g = A32 + (size_t)(m0 + row) * K + k0 + sp * 8;
                t0[it] = *(const f32x4*)g;
                t1[it] = *(const f32x4*)(g + 4);
            }
#pragma unroll
            for (int it = 0; it < 4; ++it) {
                int row = w * 32 + it * 8 + (l >> 3);
                f16x8 hx;
#pragma unroll
                for (int e = 0; e < 4; ++e) {
                    hx[e] = (f16)t0[it][e];
                    hx[e + 4] = (f16)t1[it][e];
                }
                *(f16x8*)(As + row * 64 + (sp ^ (row & 7)) * 8) = hx;
            }
#pragma unroll
            for (int it = 0; it < 4; ++it) {
                int row = w * 32 + it * 8 + (l >> 3);
                int gchunk = sp ^ (row & 7);
                const f16* gB = B + (size_t)(n0 + row) * K + k0 + gchunk * 8;
                f16* lB = Bs + (w * 32 + it * 8) * 64;
                __builtin_amdgcn_global_load_lds((const __attribute__((address_space(1))) void*)gB,
                                                 (__attribute__((address_space(3))) void*)lB, 16, 0, 0);
            }
        } else {
            const f16* A16 = (const f16*)Av;
#pragma unroll
            for (int it = 0; it < 4; ++it) {
                int row = w * 32 + it * 8 + (l >> 3);
                int gchunk = sp ^ (row & 7);
                const f16* gA = A16 + (size_t)(m0 + row) * K + k0 + gchunk * 8;
                const f16* gB = B + (size_t)(n0 + row) * K + k0 + gchunk * 8;
                f16* lA = As + (w * 32 + it * 8) * 64;  // wave-uniform; HW adds lane*16B
                f16* lB = Bs + (w * 32 + it * 8) * 64;
                __builtin_amdgcn_global_load_lds((const __attribute__((address_space(1))) void*)gA,
                                                 (__attribute__((address_space(3))) void*)lA, 16, 0, 0);
                __builtin_amdgcn_global_load_lds((const __attribute__((address_space(1))) void*)gB,
                                                 (__attribute__((address_space(3))) void*)lB, 16, 0, 0);
            }
        }
        __syncthreads();
#pragma unroll
        for (int ks = 0; ks < 2; ++ks) {
            f16x8 af[4], bfr[4];
#pragma unroll
            for (int mi = 0; mi < 4; ++mi) {
                int r = 64 * wm + 16 * mi + lr;
                int chunk = (lg + 4 * ks) ^ (r & 7);
                af[mi] = *(const f16x8*)(As + r * 64 + chunk * 8);
            }
#pragma unroll
            for (int ni = 0; ni < 4; ++ni) {
                int r = 64 * wn + 16 * ni + lr;
                int chunk = (lg + 4 * ks) ^ (r & 7);
                bfr[ni] = *(const f16x8*)(Bs + r * 64 + chunk * 8);
            }
#pragma unroll
            for (int mi = 0; mi < 4; ++mi)
#pragma unroll
                for (int ni = 0; ni < 4; ++ni)
                    acc[mi][ni] = MFMA16(af[mi], bfr[ni], acc[mi][ni]);
        }
    }
    // epilogue: C/D layout col=lane&15, row=(lane>>4)*4+reg [m89]
#pragma unroll
    for (int mi = 0; mi < 4; ++mi) {
#pragma unroll
        for (int ni = 0; ni < 4; ++ni) {
            int col = n0 + 64 * wn + 16 * ni + lr;
            float bv = bias[col];
#pragma unroll
            for (int reg = 0; reg < 4; ++reg) {
                int row = m0 + 64 * wm + 16 * mi + 4 * lg + reg;
                C[(size_t)row * N + col] = (OUT_T)(acc[mi][ni][reg] + bv);
            }
        }
    }
}

// ---------------------------------------------------------------------------
// fused attention: one block (1 wave) per (window, head)
// QK^T via MFMA (frags straight from global), V fragments prefetched from
// global into registers immediately after QK^T (T14: latency hides under the
// softmax VALU block), wave-parallel softmax, P through XOR-swizzled LDS,
// MFMA PV per stream from the prefetched registers.
// Cross-window over-reads (j>=49) are multiplied by P=0 -> harmless; ws
// buffer ordering keeps them in-bounds.
// ---------------------------------------------------------------------------
__global__ __launch_bounds__(64) void attn_kernel(const f16* __restrict__ qkv,
                                                  const f16* __restrict__ vse,
                                                  const float* __restrict__ bm_all,
                                                  f16* __restrict__ att_se, f16* __restrict__ att_de) {
    __shared__ __align__(16) f16 Ps[64 * 64];      // P, swizzled

    const int bh = blockIdx.x;
    const int b = bh / NHEAD, h = bh - b * NHEAD;
    const int l = threadIdx.x;
    const int lr = l & 15, lg = l >> 4;
    const size_t wbase = (size_t)b * NTOK;

    // QK^T : fragments directly from global (no clamps; over-reads in-bounds of ws)
    f16x8 qa[4], kb[4];
#pragma unroll
    for (int mi = 0; mi < 4; ++mi)
        qa[mi] = *(const f16x8*)(qkv + (wbase + 16 * mi + lr) * 1152 + h * 32 + lg * 8);
#pragma unroll
    for (int ni = 0; ni < 4; ++ni)
        kb[ni] = *(const f16x8*)(qkv + (wbase + 16 * ni + lr) * 1152 + 384 + h * 32 + lg * 8);

    const f32x4 zero4 = {0.f, 0.f, 0.f, 0.f};
    f32x4 S[4][4];
    __builtin_amdgcn_s_setprio(1);
#pragma unroll
    for (int mi = 0; mi < 4; ++mi)
#pragma unroll
        for (int ni = 0; ni < 4; ++ni)
            S[mi][ni] = MFMA16(qa[mi], kb[ni], zero4);
    __builtin_amdgcn_s_setprio(0);

    // T14: issue all V-fragment gathers now; they complete under the softmax
    f16x8 vbr[2][2][2];  // [stream][ks][ni]
#pragma unroll
    for (int s = 0; s < 2; ++s) {
        const f16* vbase = s ? (qkv + wbase * 1152 + 768 + h * 32) : (vse + wbase * 384 + h * 32);
        const int RS = s ? 1152 : 384;
#pragma unroll
        for (int ks = 0; ks < 2; ++ks)
#pragma unroll
            for (int ni = 0; ni < 2; ++ni) {
                const f16* p = vbase + (size_t)(8 * lg + 32 * ks) * RS + 16 * ni + lr;
#pragma unroll
                for (int e = 0; e < 8; ++e) vbr[s][ks][ni][e] = p[(size_t)e * RS];
            }
    }

    // softmax (bias+mask from precomputed table; rows spread over 16-lane groups)
    const float* bmp = bm_all + (size_t)((b & 3) * NHEAD + h) * 4096;
#pragma unroll
    for (int mi = 0; mi < 4; ++mi) {
#pragma unroll
        for (int reg = 0; reg < 4; ++reg) {
            int r = 16 * mi + 4 * lg + reg;
            float v[4];
#pragma unroll
            for (int ni = 0; ni < 4; ++ni)
                v[ni] = S[mi][ni][reg] * SCALE_F + bmp[(r << 6) + 16 * ni + lr];
            float mx = fmaxf(fmaxf(v[0], v[1]), fmaxf(v[2], v[3]));
#pragma unroll
            for (int off = 1; off < 16; off <<= 1) mx = fmaxf(mx, __shfl_xor(mx, off));
            float e[4];
            float sm = 0.f;
#pragma unroll
            for (int ni = 0; ni < 4; ++ni) {
                e[ni] = __expf(v[ni] - mx);
                sm += e[ni];
            }
#pragma unroll
            for (int off = 1; off < 16; off <<= 1) sm += __shfl_xor(sm, off);
            float inv = 1.f / sm;
#pragma unroll
            for (int ni = 0; ni < 4; ++ni)
                Ps[(r << 6) + ((16 * ni + lr) ^ ((r & 7) << 3))] = (f16)(e[ni] * inv);
        }
    }
    __syncthreads();

    // PV, one value-stream at a time (halves accumulator liveness)
#pragma unroll
    for (int s = 0; s < 2; ++s) {
        f32x4 o[4][2] = {};
#pragma unroll
        for (int ks = 0; ks < 2; ++ks) {
            f16x8 pa[4];
#pragma unroll
            for (int mi = 0; mi < 4; ++mi) {
                int r = 16 * mi + lr;
                pa[mi] = *(const f16x8*)(Ps + (r << 6) + ((8 * lg + 32 * ks) ^ ((r & 7) << 3)));
            }
            __builtin_amdgcn_s_setprio(1);
#pragma unroll
            for (int ni = 0; ni < 2; ++ni)
#pragma unroll
                for (int mi = 0; mi < 4; ++mi) o[mi][ni] = MFMA16(pa[mi], vbr[s][ks][ni], o[mi][ni]);
            __builtin_amdgcn_s_setprio(0);
        }
        f16* dst = s ? att_de : att_se;
#pragma unroll
        for (int mi = 0; mi < 4; ++mi) {
#pragma unroll
            for (int reg = 0; reg < 4; ++reg) {
                int r = 16 * mi + 4 * lg + reg;
                if (r < NTOK) {
#pragma unroll
                    for (int ni = 0; ni < 2; ++ni)
                        dst[(wbase + r) * 384 + h * 32 + 16 * ni + lr] = (f16)o[mi][ni][reg];
                }
            }
        }
    }
}

// ---------------------------------------------------------------------------
extern "C" void kernel_launch(void* const* d_in, const int* in_sizes, int n_in,
                              void* d_out, int out_size, void* d_ws, size_t ws_size,
                              hipStream_t stream) {
    const float* se = (const float*)d_in[0];
    const float* de = (const float*)d_in[1];
    const float* mask = (const float*)d_in[2];
    const float* w_v_se = (const float*)d_in[3];
    const float* b_v_se = (const float*)d_in[4];
    const float* w_qkv = (const float*)d_in[5];
    const float* b_qkv = (const float*)d_in[6];
    const float* w_proj_se = (const float*)d_in[7];
    const float* b_proj_se = (const float*)d_in[8];
    const float* w_proj_de = (const float*)d_in[9];
    const float* b_proj_de = (const float*)d_in[10];
    const float* rpb = (const float*)d_in[11];
    const int* rel_idx = (const int*)d_in[12];

    const size_t SE_ELEMS = (size_t)NBW * NTOK * 384;  // 38,535,168

    char* ws = (char*)d_ws;
    f16* att_se = (f16*)(ws);                 // (100352, 384) f16
    f16* att_de = (f16*)(ws + 77070336);      // (100352, 384) f16
    f16* qkv_h = (f16*)(ws + 154140672);      // (100352, 1152) f16
    f16* vse_h = (f16*)(ws + 385351680);      // (100352, 384) f16
    f16* wqkv_h = (f16*)(ws + 462422016);
    f16* wvse_h = (f16*)(ws + 463306752);
    f16* wpse_h = (f16*)(ws + 463601664);
    f16* wpde_h = (f16*)(ws + 463896576);
    float* bm = (float*)(ws + 464191488);

    auto cast = [&](const float* in, f16* out, size_t n) {
        int n4 = (int)(n / 4);
        int blocks = (n4 + 255) / 256;
        if (blocks > 2048) blocks = 2048;
        cast_f32_to_f16<<<blocks, 256, 0, stream>>>(in, out, n4);
    };
    cast(w_qkv, wqkv_h, (size_t)1152 * 384);
    cast(w_v_se, wvse_h, (size_t)384 * 384);
    cast(w_proj_se, wpse_h, (size_t)384 * 384);
    cast(w_proj_de, wpde_h, (size_t)384 * 384);

    prep_bm<<<48, 64, 0, stream>>>(rpb, rel_idx, mask, bm);

    // qkv = de @ w_qkv^T + b   (M=100352, N=1152, K=384), A read as f32 (fused cast)
    gemm_bt<f16, true><<<dim3(9, 784), 256, 0, stream>>>((const void*)de, wqkv_h, b_qkv, qkv_h, 100352, 1152, 384);
    // v_se = se @ w_v_se^T + b (M=100352, N=384, K=384), A read as f32 (fused cast)
    gemm_bt<f16, true><<<dim3(3, 784), 256, 0, stream>>>((const void*)se, wvse_h, b_v_se, vse_h, 100352, 384, 384);

    // attention
    attn_kernel<<<NBW * NHEAD, 64, 0, stream>>>(qkv_h, vse_h, bm, att_se, att_de);

    // projections straight into d_out (f32)
    gemm_bt<float, false><<<dim3(3, 784), 256, 0, stream>>>((const void*)att_se, wpse_h, b_proj_se, (float*)d_out,
                                                            100352, 384, 384);
    gemm_bt<float, false><<<dim3(3, 784), 256, 0, stream>>>((const void*)att_de, wpde_h, b_proj_de,
                                                            (float*)d_out + SE_ELEMS, 100352, 384, 384);
}